// Round 12
// baseline (894.403 us; speedup 1.0000x reference)
//
#include <hip/hip_runtime.h>

#define HD __device__ __forceinline__

static constexpr int H = 128;
static constexpr int G = 100;
static constexpr int L = 4;
static constexpr int C = 10;
static constexpr int DEGCAP = 64;   // per-node edge capacity (mean deg = 12)

typedef __attribute__((ext_vector_type(8))) short short8;   // 8 bf16 (4 VGPRs)
typedef __attribute__((ext_vector_type(4))) float f32x4;    // MFMA C/D

HD float bf2f(unsigned int u16) {  // low 16 bits = bf16
    return __uint_as_float(u16 << 16);
}
HD unsigned int f2bf(float f) {    // RNE pack to 16 bits
    unsigned int u = __float_as_uint(f);
    u += 0x7fffu + ((u >> 16) & 1u);
    return u >> 16;
}

// ---------------- prep: weight transpose (blocks 0..575) + edge-table fill (blocks 576..) ----------------
__global__ __launch_bounds__(256) void prep_kernel(
    const float* __restrict__ embW, const float* __restrict__ W1, const float* __restrict__ W2,
    unsigned short* __restrict__ WT, unsigned short* __restrict__ Hb,
    const int* __restrict__ src, const int* __restrict__ dst, int E,
    int* __restrict__ cnt, int* __restrict__ esrc) {
    int b = blockIdx.x;
    if (b < 576) {
        int mat = b >> 6;
        int bx = b & 63;
        if (b == 0 && threadIdx.x < 64)
            ((unsigned int*)Hb)[threadIdx.x] = 0u;   // zero row 0 (gather null target)
        const float* s = (mat == 0) ? embW
                       : (mat <= L) ? W1 + (size_t)(mat - 1) * H * H
                                    : W2 + (size_t)(mat - 1 - L) * H * H;
        int t = bx * 256 + threadIdx.x;   // 0..16383
        int col = t >> 7, k = t & 127;
        WT[(size_t)mat * H * H + col * H + k] = (unsigned short)f2bf(s[(size_t)k * H + col]);
    } else {
        int e = (b - 576) * 256 + threadIdx.x;
        if (e < E) {
            int d = dst[e];
            int pos = atomicAdd(&cnt[d], 1) & (DEGCAP - 1);
            esrc[(size_t)d * DEGCAP + pos] = src[e] + 1;   // +1: 0 = zero row
        }
    }
}

// ---------------- neighbor aggregation: padded 16-wide gather rounds ----------------
__global__ __launch_bounds__(256) void agg_kernel(const unsigned short* __restrict__ HbZ,
                                                  const int* __restrict__ cnt,
                                                  const int* __restrict__ esrc,
                                                  const float* __restrict__ eps, int layer,
                                                  unsigned short* __restrict__ ZB, int N) {
    int node = blockIdx.x * 4 + (threadIdx.x >> 6);
    int lane = threadIdx.x & 63;
    if (node >= N) return;
    const unsigned int* H2 = (const unsigned int*)HbZ;
    float e1 = 1.0f + eps[layer];
    unsigned int hv = H2[(size_t)(node + 1) * 64 + lane];
    float ax = e1 * bf2f(hv & 0xffffu);
    float ay = e1 * bf2f(hv >> 16);
    int deg = min(cnt[node], DEGCAP);
    int degPad = min((deg + 15) & ~15, DEGCAP);
    const int* ep = esrc + (size_t)node * DEGCAP;
    for (int j = 0; j < degPad; j += 16) {
        unsigned int v[16];
#pragma unroll
        for (int u = 0; u < 16; ++u) v[u] = H2[(size_t)ep[j + u] * 64 + lane];
        float sx[4] = {0.f, 0.f, 0.f, 0.f}, sy[4] = {0.f, 0.f, 0.f, 0.f};
#pragma unroll
        for (int u = 0; u < 16; ++u) {
            sx[u & 3] += bf2f(v[u] & 0xffffu);
            sy[u & 3] += bf2f(v[u] >> 16);
        }
        ax += (sx[0] + sx[1]) + (sx[2] + sx[3]);
        ay += (sy[0] + sy[1]) + (sy[2] + sy[3]);
    }
    ((unsigned int*)ZB)[(size_t)node * 64 + lane] = f2bf(ax) | (f2bf(ay) << 16);
}

// ---------------- MFMA GEMM: out = f(A) @ W + bias ----------------
template <bool ABF16, bool TRANS, bool STATS, bool POOLF, bool HOFF>
__global__ __launch_bounds__(256, 4) void mgemm_kernel(
    const float* __restrict__ Af, const unsigned short* __restrict__ Ab,
    const unsigned short* __restrict__ WT, const float* __restrict__ bias,
    const float* __restrict__ sum_in, const float* __restrict__ sq_in,
    const float* __restrict__ gam, const float* __restrict__ bet, float invN,
    unsigned short* __restrict__ outB,
    int N, float* __restrict__ sum_out, float* __restrict__ sq_out,
    const int* __restrict__ gids, float* __restrict__ pool) {
    __shared__ unsigned short As[64 * 136];
    __shared__ float cas[H], ccs[H];
    int tid = threadIdx.x;
    int w = tid >> 6, lane = tid & 63, q = lane >> 4, m = lane & 15;
    int row0 = blockIdx.x * 64;
    int colbase = w * 32;

    short8 bfrag[2][4];
#pragma unroll
    for (int nt = 0; nt < 2; ++nt) {
        const unsigned short* wc = WT + (size_t)(colbase + nt * 16 + m) * H;
#pragma unroll
        for (int kk = 0; kk < 4; ++kk)
            bfrag[nt][kk] = *(const short8*)&wc[kk * 32 + q * 8];
    }

    if (TRANS) {
        if (tid < H) {
            float mu = sum_in[tid] * invN;
            float var = sq_in[tid] * invN - mu * mu;
            float inv = rsqrtf(var + 1e-5f);
            float a = gam[tid] * inv;
            cas[tid] = a;
            ccs[tid] = bet[tid] - mu * a;
        }
        __syncthreads();
    }

    {
        int cc = tid & 15, rg = tid >> 4;
        int c0 = cc * 8;
        float a8[8], b8[8];
        if (TRANS) {
#pragma unroll
            for (int j = 0; j < 8; ++j) { a8[j] = cas[c0 + j]; b8[j] = ccs[c0 + j]; }
        }
#pragma unroll
        for (int rr = 0; rr < 4; ++rr) {
            int r = rg * 4 + rr;
            int gr = row0 + r;
            uint4 o = {0u, 0u, 0u, 0u};
            if (ABF16 && !TRANS) {
                if (gr < N) o = *(const uint4*)&Ab[(size_t)gr * H + c0];
            } else {
                float v[8] = {0.f, 0.f, 0.f, 0.f, 0.f, 0.f, 0.f, 0.f};
                if (gr < N) {
                    if (ABF16) {
                        uint4 x = *(const uint4*)&Ab[(size_t)gr * H + c0];
                        v[0] = bf2f(x.x & 0xffffu); v[1] = bf2f(x.x >> 16);
                        v[2] = bf2f(x.y & 0xffffu); v[3] = bf2f(x.y >> 16);
                        v[4] = bf2f(x.z & 0xffffu); v[5] = bf2f(x.z >> 16);
                        v[6] = bf2f(x.w & 0xffffu); v[7] = bf2f(x.w >> 16);
                    } else {
                        float4 x0 = *(const float4*)&Af[(size_t)gr * H + c0];
                        float4 x1 = *(const float4*)&Af[(size_t)gr * H + c0 + 4];
                        v[0] = x0.x; v[1] = x0.y; v[2] = x0.z; v[3] = x0.w;
                        v[4] = x1.x; v[5] = x1.y; v[6] = x1.z; v[7] = x1.w;
                    }
                }
                if (TRANS) {
#pragma unroll
                    for (int j = 0; j < 8; ++j) v[j] = fmaxf(a8[j] * v[j] + b8[j], 0.f);
                }
                o.x = f2bf(v[0]) | (f2bf(v[1]) << 16);
                o.y = f2bf(v[2]) | (f2bf(v[3]) << 16);
                o.z = f2bf(v[4]) | (f2bf(v[5]) << 16);
                o.w = f2bf(v[6]) | (f2bf(v[7]) << 16);
            }
            *(uint4*)&As[r * 136 + c0] = o;
        }
    }
    __syncthreads();

    f32x4 acc[4][2];
#pragma unroll
    for (int mt = 0; mt < 4; ++mt)
#pragma unroll
        for (int nt = 0; nt < 2; ++nt) acc[mt][nt] = (f32x4){0.f, 0.f, 0.f, 0.f};
#pragma unroll
    for (int kk = 0; kk < 4; ++kk) {
        short8 af[4];
#pragma unroll
        for (int mt = 0; mt < 4; ++mt)
            af[mt] = *(const short8*)&As[(mt * 16 + m) * 136 + kk * 32 + q * 8];
#pragma unroll
        for (int mt = 0; mt < 4; ++mt)
#pragma unroll
            for (int nt = 0; nt < 2; ++nt)
                acc[mt][nt] = __builtin_amdgcn_mfma_f32_16x16x32_bf16(
                    af[mt], bfrag[nt][kk], acc[mt][nt], 0, 0, 0);
    }

    float bs2[2] = {bias[colbase + m], bias[colbase + 16 + m]};
    float s[2] = {0.f, 0.f}, qq[2] = {0.f, 0.f};
#pragma unroll
    for (int mt = 0; mt < 4; ++mt)
#pragma unroll
        for (int nt = 0; nt < 2; ++nt) {
            int gcol = colbase + nt * 16 + m;
#pragma unroll
            for (int rg = 0; rg < 4; ++rg) {
                int grow = row0 + mt * 16 + q * 4 + rg;
                float v = acc[mt][nt][rg] + bs2[nt];
                if (grow < N) {
                    outB[(size_t)(HOFF ? grow + 1 : grow) * H + gcol] = (unsigned short)f2bf(v);
                    if (STATS || POOLF) {
                        s[nt] += v;
                        if (STATS) qq[nt] += v * v;
                    }
                }
            }
        }

    if (STATS) {
#pragma unroll
        for (int nt = 0; nt < 2; ++nt) {
            float sv = s[nt], qv = qq[nt];
            sv += __shfl_xor(sv, 16); sv += __shfl_xor(sv, 32);
            qv += __shfl_xor(qv, 16); qv += __shfl_xor(qv, 32);
            if (q == 0) {
                atomicAdd(&sum_out[colbase + nt * 16 + m], sv);
                atomicAdd(&sq_out[colbase + nt * 16 + m], qv);
            }
        }
    }

    if (POOLF) {
        int last = min(row0 + 63, N - 1);
        bool uni = (gids[row0] == gids[last]);
        if (uni) {
            int g = gids[row0];
#pragma unroll
            for (int nt = 0; nt < 2; ++nt) {
                float sv = s[nt];
                sv += __shfl_xor(sv, 16); sv += __shfl_xor(sv, 32);
                if (q == 0) atomicAdd(&pool[g * H + colbase + nt * 16 + m], sv);
            }
        } else {
#pragma unroll
            for (int mt = 0; mt < 4; ++mt)
#pragma unroll
                for (int nt = 0; nt < 2; ++nt)
#pragma unroll
                    for (int rg = 0; rg < 4; ++rg) {
                        int grow = row0 + mt * 16 + q * 4 + rg;
                        if (grow < N) {
                            float v = acc[mt][nt][rg] + bs2[nt];
                            atomicAdd(&pool[gids[grow] * H + colbase + nt * 16 + m], v);
                        }
                    }
        }
    }
}

// ---------------- merged statsv + tail, one spin barrier (grid must be co-resident) ----------------
// launch_bounds(256,2): 2 blocks/CU guaranteed -> grid of 512 blocks always co-resident.
__global__ __launch_bounds__(256, 2) void stv_tail_kernel(
    unsigned short* __restrict__ HbZ, const unsigned short* __restrict__ UB,
    const float* __restrict__ snorm,
    const float* __restrict__ S2, const float* __restrict__ Q2,
    const float* __restrict__ ga, const float* __restrict__ ba,
    float* __restrict__ S3, float* __restrict__ Q3,
    const float* __restrict__ gl, const float* __restrict__ bl,
    float invN, const int* __restrict__ gids, float* __restrict__ pool,
    int N, int* __restrict__ bar) {
    __shared__ float c1[H], c2[H], c3[H], c4[H];
    __shared__ float SS[4][H], QQ[4][H];   // reused as PS[8][H] in phase 2
    int t = threadIdx.x;

    // ---- phase 1: statsv (BN2 coeffs inline from S2/Q2; accumulate S3/Q3) ----
    if (t < H) {
        float mu = S2[t] * invN;
        float var = Q2[t] * invN - mu * mu;
        float inv = rsqrtf(var + 1e-5f);
        float a = ga[t] * inv;
        c1[t] = a;
        c2[t] = ba[t] - mu * a;
    }
    __syncthreads();
    {
        int col2 = t & 63, part = t >> 6;
        int cA = col2 * 2, cB = cA + 1;
        float a0 = c1[cA], b0 = c2[cA], a1 = c1[cB], b1 = c2[cB];
        float s0 = 0.f, q0 = 0.f, s1 = 0.f, q1 = 0.f;
        const unsigned int* U2 = (const unsigned int*)UB;
        for (int r = blockIdx.x * 4 + part; r < N; r += gridDim.x * 4) {
            float sn = snorm[r];
            unsigned int v = U2[(size_t)r * 64 + col2];
            float v0 = fmaxf(a0 * bf2f(v & 0xffffu) + b0, 0.f) * sn;
            float v1 = fmaxf(a1 * bf2f(v >> 16) + b1, 0.f) * sn;
            s0 += v0; q0 += v0 * v0;
            s1 += v1; q1 += v1 * v1;
        }
        SS[part][cA] = s0; SS[part][cB] = s1;
        QQ[part][cA] = q0; QQ[part][cB] = q1;
        __syncthreads();
        if (t < H) {
            atomicAdd(&S3[t], SS[0][t] + SS[1][t] + SS[2][t] + SS[3][t]);
            atomicAdd(&Q3[t], QQ[0][t] + QQ[1][t] + QQ[2][t] + QQ[3][t]);
        }
        __syncthreads();
    }

    // ---- spin barrier (all blocks co-resident by launch_bounds construction) ----
    if (t == 0) {
        __threadfence();
        atomicAdd(bar, 1);
        while (__hip_atomic_load(bar, __ATOMIC_RELAXED, __HIP_MEMORY_SCOPE_AGENT) < (int)gridDim.x)
            __builtin_amdgcn_s_sleep(2);
    }
    __syncthreads();
    __threadfence();

    // ---- phase 2: tail (BN3 coeffs from complete S3/Q3; residual + pool) ----
    if (t < H) {
        float m3 = S3[t] * invN, v3 = Q3[t] * invN - m3 * m3;
        float i3 = rsqrtf(v3 + 1e-5f), a3 = gl[t] * i3;
        c3[t] = a3;
        c4[t] = bl[t] - m3 * a3;
    }
    __syncthreads();
    float* PS = &SS[0][0];   // 8*H floats (SS+QQ contiguous)
    int col4 = t & 31, rowg = t >> 5;
    int c0 = col4 * 4;
    float A2[4], B2[4], A3[4], B3[4];
#pragma unroll
    for (int j = 0; j < 4; ++j) {
        A2[j] = c1[c0 + j]; B2[j] = c2[c0 + j];
        A3[j] = c3[c0 + j]; B3[j] = c4[c0 + j];
    }
    const uint2* U4 = (const uint2*)UB;
    uint2* H4 = (uint2*)HbZ;
    int tiles32 = (N + 31) / 32;
    for (int t32 = blockIdx.x; t32 < tiles32; t32 += gridDim.x) {
        int row0 = t32 * 32;
        bool uni = (gids[row0] == gids[min(row0 + 31, N - 1)]);
        float p[4] = {0.f, 0.f, 0.f, 0.f};
#pragma unroll
        for (int rr = 0; rr < 4; ++rr) {
            int r = row0 + rowg * 4 + rr;
            if (r < N) {
                float sn = snorm[r];
                uint2 uv = U4[(size_t)r * 32 + col4];
                uint2 hv = H4[(size_t)(r + 1) * 32 + col4];
                float u[4] = {bf2f(uv.x & 0xffffu), bf2f(uv.x >> 16),
                              bf2f(uv.y & 0xffffu), bf2f(uv.y >> 16)};
                float h[4] = {bf2f(hv.x & 0xffffu), bf2f(hv.x >> 16),
                              bf2f(hv.y & 0xffffu), bf2f(hv.y >> 16)};
#pragma unroll
                for (int j = 0; j < 4; ++j) {
                    float v = fmaxf(A2[j] * u[j] + B2[j], 0.f) * sn;
                    h[j] += fmaxf(A3[j] * v + B3[j], 0.f);
                }
                uint2 hb;
                hb.x = f2bf(h[0]) | (f2bf(h[1]) << 16);
                hb.y = f2bf(h[2]) | (f2bf(h[3]) << 16);
                H4[(size_t)(r + 1) * 32 + col4] = hb;
                if (uni) {
                    p[0] += h[0]; p[1] += h[1]; p[2] += h[2]; p[3] += h[3];
                } else {
                    int g = gids[r];
#pragma unroll
                    for (int j = 0; j < 4; ++j) atomicAdd(&pool[g * H + c0 + j], h[j]);
                }
            }
        }
        if (uni) {
#pragma unroll
            for (int j = 0; j < 4; ++j) PS[rowg * H + c0 + j] = p[j];
            __syncthreads();
            if (t < H) {
                float s = PS[t] + PS[H + t] + PS[2 * H + t] + PS[3 * H + t] +
                          PS[4 * H + t] + PS[5 * H + t] + PS[6 * H + t] + PS[7 * H + t];
                atomicAdd(&pool[gids[row0] * H + t], s);
            }
            __syncthreads();
        }
    }
}

// ---------------- final: score = sum_i pooled_i @ predW_i + predb_i ----------------
__global__ void final_kernel(const float* __restrict__ pool, const float* __restrict__ pw,
                             const float* __restrict__ pb, float* __restrict__ out) {
    int g = blockIdx.x, t = threadIdx.x;
    __shared__ float p[H];
    float acc = 0.f;
    for (int i = 0; i <= L; ++i) {
        p[t] = pool[(size_t)(i * G + g) * H + t];
        __syncthreads();
        if (t < C) {
            float s = 0.f;
            for (int f = 0; f < H; ++f) s += p[f] * pw[(size_t)(i * H + f) * C + t];
            acc += s + pb[i * C + t];
        }
        __syncthreads();
    }
    if (t < C) out[g * C + t] = acc;
}

extern "C" void kernel_launch(void* const* d_in, const int* in_sizes, int n_in,
                              void* d_out, int out_size, void* d_ws, size_t ws_size,
                              hipStream_t stream) {
    const float* h_in  = (const float*)d_in[0];
    const float* snorm = (const float*)d_in[1];
    const int* esrc_in = (const int*)d_in[2];
    const int* edst_in = (const int*)d_in[3];
    const int* gids    = (const int*)d_in[4];
    const float* embW = (const float*)d_in[5];
    const float* embB = (const float*)d_in[6];
    const float* eps  = (const float*)d_in[7];
    const float* W1   = (const float*)d_in[8];
    const float* b1   = (const float*)d_in[9];
    const float* g1   = (const float*)d_in[10];
    const float* be1  = (const float*)d_in[11];
    const float* W2   = (const float*)d_in[12];
    const float* b2   = (const float*)d_in[13];
    const float* ga   = (const float*)d_in[14];
    const float* ba   = (const float*)d_in[15];
    const float* gl   = (const float*)d_in[16];
    const float* bl   = (const float*)d_in[17];
    const float* predW = (const float*)d_in[18];
    const float* predB = (const float*)d_in[19];

    const int N = in_sizes[0] / H;  // 50000
    const int E = in_sizes[2];      // 600000
    const float invN = 1.0f / (float)N;

    // ws layout: [zeroed: POOL | STATS | BAR | CNT | ESRC] [WT] [Hb (N+1 rows)] [ZB] [TB]
    float* ws = (float*)d_ws;
    float* POOL = ws;                                        // (L+1)*G*H
    float* STATS = POOL + (size_t)(L + 1) * G * H;           // L*6*H
    int* BAR = (int*)(STATS + (size_t)L * 6 * H);            // 16 ints (one per layer used)
    int* CNT = BAR + 16;                                     // N
    int* ESRC = CNT + N;                                     // N*DEGCAP (pre-zeroed => pad -> row 0)
    unsigned short* WT = (unsigned short*)(ESRC + (size_t)N * DEGCAP);  // 9*H*H bf16
    unsigned short* Hb = WT + (size_t)9 * H * H;             // (N+1)*H bf16, row 0 = zeros
    unsigned short* ZB = Hb + (size_t)(N + 1) * H;           // N*H bf16
    unsigned short* TB = ZB + (size_t)N * H;                 // N*H bf16
    unsigned short* UB = ZB;                                 // alias: ZB dead when UB written

    size_t zbytes = ((size_t)(L + 1) * G * H + (size_t)L * 6 * H + 16 + N + (size_t)N * DEGCAP) * 4;
    hipMemsetAsync(POOL, 0, zbytes, stream);

    int prep_blocks = 576 + (E + 255) / 256;
    prep_kernel<<<prep_blocks, 256, 0, stream>>>(embW, W1, W2, WT, Hb,
                                                 esrc_in, edst_in, E, CNT, ESRC);

    int gblocks = (N + 63) / 64;
    // embedding: A=f32 h_in -> Hb rows 1..N, fused pool into POOL[0]
    mgemm_kernel<false, false, false, true, true><<<gblocks, 256, 0, stream>>>(
        h_in, nullptr, WT, embB, nullptr, nullptr, nullptr, nullptr, invN,
        Hb, N, nullptr, nullptr, gids, POOL);

    for (int i = 0; i < L; ++i) {
        float* S1 = STATS + (size_t)i * 6 * H;
        float* Q1 = S1 + H;
        float* S2 = Q1 + H;
        float* Q2 = S2 + H;
        float* S3 = Q2 + H;
        float* Q3 = S3 + H;
        agg_kernel<<<(N + 3) / 4, 256, 0, stream>>>(Hb, CNT, ESRC, eps, i, ZB, N);
        // gemm1: A=ZB bf16 -> TB bf16, stats S1/Q1
        mgemm_kernel<true, false, true, false, false><<<gblocks, 256, 0, stream>>>(
            nullptr, ZB, WT + (size_t)(1 + i) * H * H, b1 + (size_t)i * H,
            nullptr, nullptr, nullptr, nullptr, invN,
            TB, N, S1, Q1, nullptr, nullptr);
        // gemm2: A=TB bf16 with BN1-affine+relu -> UB bf16, stats S2/Q2
        mgemm_kernel<true, true, true, false, false><<<gblocks, 256, 0, stream>>>(
            nullptr, TB, WT + (size_t)(1 + L + i) * H * H, b2 + (size_t)i * H,
            S1, Q1, g1 + (size_t)i * H, be1 + (size_t)i * H, invN,
            UB, N, S2, Q2, nullptr, nullptr);
        // merged statsv + tail (one spin barrier; grid 512 co-resident by launch_bounds(256,2))
        stv_tail_kernel<<<512, 256, 0, stream>>>(Hb, UB, snorm, S2, Q2,
                                                 ga + (size_t)i * H, ba + (size_t)i * H,
                                                 S3, Q3, gl + (size_t)i * H, bl + (size_t)i * H,
                                                 invN, gids, POOL + (size_t)(i + 1) * G * H,
                                                 N, BAR + i);
    }
    final_kernel<<<G, H, 0, stream>>>(POOL, predW, predB, (float*)d_out);
}

// Round 13
// 693.186 us; speedup vs baseline: 1.2903x; 1.2903x over previous
//
#include <hip/hip_runtime.h>

#define HD __device__ __forceinline__

static constexpr int H = 128;
static constexpr int G = 100;
static constexpr int L = 4;
static constexpr int C = 10;
static constexpr int DEGCAP = 64;   // per-node edge capacity (mean deg = 12)

typedef __attribute__((ext_vector_type(8))) short short8;   // 8 bf16 (4 VGPRs)
typedef __attribute__((ext_vector_type(4))) float f32x4;    // MFMA C/D

HD float bf2f(unsigned int u16) {  // low 16 bits = bf16
    return __uint_as_float(u16 << 16);
}
HD unsigned int f2bf(float f) {    // RNE pack to 16 bits
    unsigned int u = __float_as_uint(f);
    u += 0x7fffu + ((u >> 16) & 1u);
    return u >> 16;
}

// ---------------- prep: weight transpose (blocks 0..575) + edge-table fill (blocks 576..) ----------------
__global__ __launch_bounds__(256) void prep_kernel(
    const float* __restrict__ embW, const float* __restrict__ W1, const float* __restrict__ W2,
    unsigned short* __restrict__ WT, unsigned short* __restrict__ Hb,
    const int* __restrict__ src, const int* __restrict__ dst, int E,
    int* __restrict__ cnt, int* __restrict__ esrc) {
    int b = blockIdx.x;
    if (b < 576) {
        int mat = b >> 6;
        int bx = b & 63;
        if (b == 0 && threadIdx.x < 64)
            ((unsigned int*)Hb)[threadIdx.x] = 0u;   // zero row 0 (gather null target)
        const float* s = (mat == 0) ? embW
                       : (mat <= L) ? W1 + (size_t)(mat - 1) * H * H
                                    : W2 + (size_t)(mat - 1 - L) * H * H;
        int t = bx * 256 + threadIdx.x;   // 0..16383
        int col = t >> 7, k = t & 127;
        WT[(size_t)mat * H * H + col * H + k] = (unsigned short)f2bf(s[(size_t)k * H + col]);
    } else {
        int e = (b - 576) * 256 + threadIdx.x;
        if (e < E) {
            int d = dst[e];
            int pos = atomicAdd(&cnt[d], 1) & (DEGCAP - 1);
            esrc[(size_t)d * DEGCAP + pos] = src[e] + 1;   // +1: 0 = zero row
        }
    }
}

// ---------------- neighbor aggregation: padded 16-wide gather rounds ----------------
// HbZ row 0 = zeros; node n's features at HbZ row n+1.  ESRC pad slots = 0.
__global__ __launch_bounds__(256) void agg_kernel(const unsigned short* __restrict__ HbZ,
                                                  const int* __restrict__ cnt,
                                                  const int* __restrict__ esrc,
                                                  const float* __restrict__ eps, int layer,
                                                  unsigned short* __restrict__ ZB, int N) {
    int node = blockIdx.x * 4 + (threadIdx.x >> 6);
    int lane = threadIdx.x & 63;
    if (node >= N) return;
    const unsigned int* H2 = (const unsigned int*)HbZ;
    float e1 = 1.0f + eps[layer];
    unsigned int hv = H2[(size_t)(node + 1) * 64 + lane];
    float ax = e1 * bf2f(hv & 0xffffu);
    float ay = e1 * bf2f(hv >> 16);
    int deg = min(cnt[node], DEGCAP);
    int degPad = min((deg + 15) & ~15, DEGCAP);
    const int* ep = esrc + (size_t)node * DEGCAP;
    for (int j = 0; j < degPad; j += 16) {
        unsigned int v[16];
#pragma unroll
        for (int u = 0; u < 16; ++u) v[u] = H2[(size_t)ep[j + u] * 64 + lane];
        float sx[4] = {0.f, 0.f, 0.f, 0.f}, sy[4] = {0.f, 0.f, 0.f, 0.f};
#pragma unroll
        for (int u = 0; u < 16; ++u) {
            sx[u & 3] += bf2f(v[u] & 0xffffu);
            sy[u & 3] += bf2f(v[u] >> 16);
        }
        ax += (sx[0] + sx[1]) + (sx[2] + sx[3]);
        ay += (sy[0] + sy[1]) + (sy[2] + sy[3]);
    }
    ((unsigned int*)ZB)[(size_t)node * 64 + lane] = f2bf(ax) | (f2bf(ay) << 16);
}

// ---------------- MFMA GEMM: out = f(A) @ W + bias ----------------
// Block: 256 thr / 4 waves; 64 rows x 128 cols; wave w owns cols w*32..+31.
// WT is bf16 col-major [col*128 + k]. ABF16: A bf16 (else f32).
// TRANS: f(A)=relu(ca*A+cc), coeffs from sum_in/sq_in.
// STATS: column sum/sumsq of out. POOLF: segment-pool of out. Output bf16 (HOFF row offset).
template <bool ABF16, bool TRANS, bool STATS, bool POOLF, bool HOFF>
__global__ __launch_bounds__(256, 4) void mgemm_kernel(
    const float* __restrict__ Af, const unsigned short* __restrict__ Ab,
    const unsigned short* __restrict__ WT, const float* __restrict__ bias,
    const float* __restrict__ sum_in, const float* __restrict__ sq_in,
    const float* __restrict__ gam, const float* __restrict__ bet, float invN,
    unsigned short* __restrict__ outB,
    int N, float* __restrict__ sum_out, float* __restrict__ sq_out,
    const int* __restrict__ gids, float* __restrict__ pool) {
    __shared__ unsigned short As[64 * 136];
    __shared__ float cas[H], ccs[H];
    int tid = threadIdx.x;
    int w = tid >> 6, lane = tid & 63, q = lane >> 4, m = lane & 15;
    int row0 = blockIdx.x * 64;
    int colbase = w * 32;

    short8 bfrag[2][4];
#pragma unroll
    for (int nt = 0; nt < 2; ++nt) {
        const unsigned short* wc = WT + (size_t)(colbase + nt * 16 + m) * H;
#pragma unroll
        for (int kk = 0; kk < 4; ++kk)
            bfrag[nt][kk] = *(const short8*)&wc[kk * 32 + q * 8];
    }

    if (TRANS) {
        if (tid < H) {
            float mu = sum_in[tid] * invN;
            float var = sq_in[tid] * invN - mu * mu;
            float inv = rsqrtf(var + 1e-5f);
            float a = gam[tid] * inv;
            cas[tid] = a;
            ccs[tid] = bet[tid] - mu * a;
        }
        __syncthreads();
    }

    {
        int cc = tid & 15, rg = tid >> 4;
        int c0 = cc * 8;
        float a8[8], b8[8];
        if (TRANS) {
#pragma unroll
            for (int j = 0; j < 8; ++j) { a8[j] = cas[c0 + j]; b8[j] = ccs[c0 + j]; }
        }
#pragma unroll
        for (int rr = 0; rr < 4; ++rr) {
            int r = rg * 4 + rr;
            int gr = row0 + r;
            uint4 o = {0u, 0u, 0u, 0u};
            if (ABF16 && !TRANS) {
                if (gr < N) o = *(const uint4*)&Ab[(size_t)gr * H + c0];
            } else {
                float v[8] = {0.f, 0.f, 0.f, 0.f, 0.f, 0.f, 0.f, 0.f};
                if (gr < N) {
                    if (ABF16) {
                        uint4 x = *(const uint4*)&Ab[(size_t)gr * H + c0];
                        v[0] = bf2f(x.x & 0xffffu); v[1] = bf2f(x.x >> 16);
                        v[2] = bf2f(x.y & 0xffffu); v[3] = bf2f(x.y >> 16);
                        v[4] = bf2f(x.z & 0xffffu); v[5] = bf2f(x.z >> 16);
                        v[6] = bf2f(x.w & 0xffffu); v[7] = bf2f(x.w >> 16);
                    } else {
                        float4 x0 = *(const float4*)&Af[(size_t)gr * H + c0];
                        float4 x1 = *(const float4*)&Af[(size_t)gr * H + c0 + 4];
                        v[0] = x0.x; v[1] = x0.y; v[2] = x0.z; v[3] = x0.w;
                        v[4] = x1.x; v[5] = x1.y; v[6] = x1.z; v[7] = x1.w;
                    }
                }
                if (TRANS) {
#pragma unroll
                    for (int j = 0; j < 8; ++j) v[j] = fmaxf(a8[j] * v[j] + b8[j], 0.f);
                }
                o.x = f2bf(v[0]) | (f2bf(v[1]) << 16);
                o.y = f2bf(v[2]) | (f2bf(v[3]) << 16);
                o.z = f2bf(v[4]) | (f2bf(v[5]) << 16);
                o.w = f2bf(v[6]) | (f2bf(v[7]) << 16);
            }
            *(uint4*)&As[r * 136 + c0] = o;
        }
    }
    __syncthreads();

    f32x4 acc[4][2];
#pragma unroll
    for (int mt = 0; mt < 4; ++mt)
#pragma unroll
        for (int nt = 0; nt < 2; ++nt) acc[mt][nt] = (f32x4){0.f, 0.f, 0.f, 0.f};
#pragma unroll
    for (int kk = 0; kk < 4; ++kk) {
        short8 af[4];
#pragma unroll
        for (int mt = 0; mt < 4; ++mt)
            af[mt] = *(const short8*)&As[(mt * 16 + m) * 136 + kk * 32 + q * 8];
#pragma unroll
        for (int mt = 0; mt < 4; ++mt)
#pragma unroll
            for (int nt = 0; nt < 2; ++nt)
                acc[mt][nt] = __builtin_amdgcn_mfma_f32_16x16x32_bf16(
                    af[mt], bfrag[nt][kk], acc[mt][nt], 0, 0, 0);
    }

    float bs2[2] = {bias[colbase + m], bias[colbase + 16 + m]};
    float s[2] = {0.f, 0.f}, qq[2] = {0.f, 0.f};
#pragma unroll
    for (int mt = 0; mt < 4; ++mt)
#pragma unroll
        for (int nt = 0; nt < 2; ++nt) {
            int gcol = colbase + nt * 16 + m;
#pragma unroll
            for (int rg = 0; rg < 4; ++rg) {
                int grow = row0 + mt * 16 + q * 4 + rg;
                float v = acc[mt][nt][rg] + bs2[nt];
                if (grow < N) {
                    outB[(size_t)(HOFF ? grow + 1 : grow) * H + gcol] = (unsigned short)f2bf(v);
                    if (STATS || POOLF) {
                        s[nt] += v;
                        if (STATS) qq[nt] += v * v;
                    }
                }
            }
        }

    if (STATS) {
#pragma unroll
        for (int nt = 0; nt < 2; ++nt) {
            float sv = s[nt], qv = qq[nt];
            sv += __shfl_xor(sv, 16); sv += __shfl_xor(sv, 32);
            qv += __shfl_xor(qv, 16); qv += __shfl_xor(qv, 32);
            if (q == 0) {
                atomicAdd(&sum_out[colbase + nt * 16 + m], sv);
                atomicAdd(&sq_out[colbase + nt * 16 + m], qv);
            }
        }
    }

    if (POOLF) {
        int last = min(row0 + 63, N - 1);
        bool uni = (gids[row0] == gids[last]);
        if (uni) {
            int g = gids[row0];
#pragma unroll
            for (int nt = 0; nt < 2; ++nt) {
                float sv = s[nt];
                sv += __shfl_xor(sv, 16); sv += __shfl_xor(sv, 32);
                if (q == 0) atomicAdd(&pool[g * H + colbase + nt * 16 + m], sv);
            }
        } else {
#pragma unroll
            for (int mt = 0; mt < 4; ++mt)
#pragma unroll
                for (int nt = 0; nt < 2; ++nt)
#pragma unroll
                    for (int rg = 0; rg < 4; ++rg) {
                        int grow = row0 + mt * 16 + q * 4 + rg;
                        if (grow < N) {
                            float v = acc[mt][nt][rg] + bs2[nt];
                            atomicAdd(&pool[gids[grow] * H + colbase + nt * 16 + m], v);
                        }
                    }
        }
    }
}

// ---------------- stats of v = relu(ca*U+cc)*snorm, coeffs computed inline ----------------
__global__ __launch_bounds__(256) void statsv_kernel(const unsigned short* __restrict__ UB,
                                                     const float* __restrict__ snorm,
                                                     const float* __restrict__ sum2, const float* __restrict__ sq2,
                                                     const float* __restrict__ ga, const float* __restrict__ ba,
                                                     float invN, int N,
                                                     float* __restrict__ sum3, float* __restrict__ sq3) {
    __shared__ float cas[H], ccs[H];
    int t = threadIdx.x;
    if (t < H) {
        float m = sum2[t] * invN;
        float var = sq2[t] * invN - m * m;
        float inv = rsqrtf(var + 1e-5f);
        float a = ga[t] * inv;
        cas[t] = a;
        ccs[t] = ba[t] - m * a;
    }
    __syncthreads();
    int col2 = t & 63, part = t >> 6;
    int c0 = col2 * 2, c1 = c0 + 1;
    float a0 = cas[c0], b0 = ccs[c0], a1 = cas[c1], b1 = ccs[c1];
    float s0 = 0.f, q0 = 0.f, s1 = 0.f, q1 = 0.f;
    const unsigned int* U2 = (const unsigned int*)UB;
    for (int r = blockIdx.x * 4 + part; r < N; r += gridDim.x * 4) {
        float sn = snorm[r];
        unsigned int v = U2[(size_t)r * 64 + col2];
        float v0 = fmaxf(a0 * bf2f(v & 0xffffu) + b0, 0.f) * sn;
        float v1 = fmaxf(a1 * bf2f(v >> 16) + b1, 0.f) * sn;
        s0 += v0; q0 += v0 * v0;
        s1 += v1; q1 += v1 * v1;
    }
    __shared__ float S[4][H], Q[4][H];
    S[part][c0] = s0; S[part][c1] = s1;
    Q[part][c0] = q0; Q[part][c1] = q1;
    __syncthreads();
    if (t < H) {
        atomicAdd(&sum3[t], S[0][t] + S[1][t] + S[2][t] + S[3][t]);
        atomicAdd(&sq3[t], Q[0][t] + Q[1][t] + Q[2][t] + Q[3][t]);
    }
}

// ---------------- residual tail (bf16 residual, rows shifted +1) + fused pooling ----------------
__global__ __launch_bounds__(256) void tail_kernel(unsigned short* __restrict__ HbZ,
                                                   const unsigned short* __restrict__ UB,
                                                   const float* __restrict__ snorm,
                                                   const float* __restrict__ sum2, const float* __restrict__ sq2,
                                                   const float* __restrict__ ga, const float* __restrict__ ba,
                                                   const float* __restrict__ sum3, const float* __restrict__ sq3,
                                                   const float* __restrict__ gl, const float* __restrict__ bl,
                                                   float invN, const int* __restrict__ gids,
                                                   float* __restrict__ pool, int N) {
    __shared__ float ca2[H], cc2[H], ca3[H], cc3[H];
    __shared__ float PS[8][H];
    int t = threadIdx.x;
    if (t < H) {
        float m2 = sum2[t] * invN, v2 = sq2[t] * invN - m2 * m2;
        float i2 = rsqrtf(v2 + 1e-5f), a2 = ga[t] * i2;
        ca2[t] = a2; cc2[t] = ba[t] - m2 * a2;
        float m3 = sum3[t] * invN, v3 = sq3[t] * invN - m3 * m3;
        float i3 = rsqrtf(v3 + 1e-5f), a3 = gl[t] * i3;
        ca3[t] = a3; cc3[t] = bl[t] - m3 * a3;
    }
    __syncthreads();
    int row0 = blockIdx.x * 32;
    int col4 = t & 31, rowg = t >> 5;
    int c0 = col4 * 4;
    float A2[4], B2[4], A3[4], B3[4];
#pragma unroll
    for (int j = 0; j < 4; ++j) {
        A2[j] = ca2[c0 + j]; B2[j] = cc2[c0 + j];
        A3[j] = ca3[c0 + j]; B3[j] = cc3[c0 + j];
    }
    bool uni = (gids[row0] == gids[min(row0 + 31, N - 1)]);
    float p[4] = {0.f, 0.f, 0.f, 0.f};
    const uint2* U4 = (const uint2*)UB;
    uint2* H4 = (uint2*)HbZ;
#pragma unroll
    for (int rr = 0; rr < 4; ++rr) {
        int r = row0 + rowg * 4 + rr;
        if (r < N) {
            float sn = snorm[r];
            uint2 uv = U4[(size_t)r * 32 + col4];
            uint2 hv = H4[(size_t)(r + 1) * 32 + col4];
            float u[4] = {bf2f(uv.x & 0xffffu), bf2f(uv.x >> 16), bf2f(uv.y & 0xffffu), bf2f(uv.y >> 16)};
            float h[4] = {bf2f(hv.x & 0xffffu), bf2f(hv.x >> 16), bf2f(hv.y & 0xffffu), bf2f(hv.y >> 16)};
#pragma unroll
            for (int j = 0; j < 4; ++j) {
                float v = fmaxf(A2[j] * u[j] + B2[j], 0.f) * sn;
                h[j] += fmaxf(A3[j] * v + B3[j], 0.f);
            }
            uint2 hb;
            hb.x = f2bf(h[0]) | (f2bf(h[1]) << 16);
            hb.y = f2bf(h[2]) | (f2bf(h[3]) << 16);
            H4[(size_t)(r + 1) * 32 + col4] = hb;
            if (uni) {
                p[0] += h[0]; p[1] += h[1]; p[2] += h[2]; p[3] += h[3];
            } else {
                int g = gids[r];
#pragma unroll
                for (int j = 0; j < 4; ++j) atomicAdd(&pool[g * H + c0 + j], h[j]);
            }
        }
    }
    if (uni) {
#pragma unroll
        for (int j = 0; j < 4; ++j) PS[rowg][c0 + j] = p[j];
        __syncthreads();
        if (t < H) {
            float s = PS[0][t] + PS[1][t] + PS[2][t] + PS[3][t] +
                      PS[4][t] + PS[5][t] + PS[6][t] + PS[7][t];
            atomicAdd(&pool[gids[row0] * H + t], s);
        }
    }
}

// ---------------- final: score = sum_i pooled_i @ predW_i + predb_i ----------------
__global__ void final_kernel(const float* __restrict__ pool, const float* __restrict__ pw,
                             const float* __restrict__ pb, float* __restrict__ out) {
    int g = blockIdx.x, t = threadIdx.x;
    __shared__ float p[H];
    float acc = 0.f;
    for (int i = 0; i <= L; ++i) {
        p[t] = pool[(size_t)(i * G + g) * H + t];
        __syncthreads();
        if (t < C) {
            float s = 0.f;
            for (int f = 0; f < H; ++f) s += p[f] * pw[(size_t)(i * H + f) * C + t];
            acc += s + pb[i * C + t];
        }
        __syncthreads();
    }
    if (t < C) out[g * C + t] = acc;
}

extern "C" void kernel_launch(void* const* d_in, const int* in_sizes, int n_in,
                              void* d_out, int out_size, void* d_ws, size_t ws_size,
                              hipStream_t stream) {
    const float* h_in  = (const float*)d_in[0];
    const float* snorm = (const float*)d_in[1];
    const int* esrc_in = (const int*)d_in[2];
    const int* edst_in = (const int*)d_in[3];
    const int* gids    = (const int*)d_in[4];
    const float* embW = (const float*)d_in[5];
    const float* embB = (const float*)d_in[6];
    const float* eps  = (const float*)d_in[7];
    const float* W1   = (const float*)d_in[8];
    const float* b1   = (const float*)d_in[9];
    const float* g1   = (const float*)d_in[10];
    const float* be1  = (const float*)d_in[11];
    const float* W2   = (const float*)d_in[12];
    const float* b2   = (const float*)d_in[13];
    const float* ga   = (const float*)d_in[14];
    const float* ba   = (const float*)d_in[15];
    const float* gl   = (const float*)d_in[16];
    const float* bl   = (const float*)d_in[17];
    const float* predW = (const float*)d_in[18];
    const float* predB = (const float*)d_in[19];

    const int N = in_sizes[0] / H;  // 50000
    const int E = in_sizes[2];      // 600000
    const float invN = 1.0f / (float)N;

    // ws layout: [zeroed: POOL | STATS | CNT | ESRC] [WT] [Hb (N+1 rows)] [ZB] [TB]
    float* ws = (float*)d_ws;
    float* POOL = ws;                                        // (L+1)*G*H
    float* STATS = POOL + (size_t)(L + 1) * G * H;           // L*6*H
    int* CNT = (int*)(STATS + (size_t)L * 6 * H);            // N
    int* ESRC = CNT + N;                                     // N*DEGCAP (pre-zeroed => pad -> row 0)
    unsigned short* WT = (unsigned short*)(ESRC + (size_t)N * DEGCAP);  // 9*H*H bf16
    unsigned short* Hb = WT + (size_t)9 * H * H;             // (N+1)*H bf16, row 0 = zeros
    unsigned short* ZB = Hb + (size_t)(N + 1) * H;           // N*H bf16
    unsigned short* TB = ZB + (size_t)N * H;                 // N*H bf16
    unsigned short* UB = ZB;                                 // alias: ZB dead when UB written

    size_t zbytes = ((size_t)(L + 1) * G * H + (size_t)L * 6 * H + N + (size_t)N * DEGCAP) * 4;
    hipMemsetAsync(POOL, 0, zbytes, stream);

    int prep_blocks = 576 + (E + 255) / 256;
    prep_kernel<<<prep_blocks, 256, 0, stream>>>(embW, W1, W2, WT, Hb,
                                                 esrc_in, edst_in, E, CNT, ESRC);

    int gblocks = (N + 63) / 64;
    // embedding: A=f32 h_in -> Hb rows 1..N, fused pool into POOL[0]
    mgemm_kernel<false, false, false, true, true><<<gblocks, 256, 0, stream>>>(
        h_in, nullptr, WT, embB, nullptr, nullptr, nullptr, nullptr, invN,
        Hb, N, nullptr, nullptr, gids, POOL);

    for (int i = 0; i < L; ++i) {
        float* S1 = STATS + (size_t)i * 6 * H;
        float* Q1 = S1 + H;
        float* S2 = Q1 + H;
        float* Q2 = S2 + H;
        float* S3 = Q2 + H;
        float* Q3 = S3 + H;
        agg_kernel<<<(N + 3) / 4, 256, 0, stream>>>(Hb, CNT, ESRC, eps, i, ZB, N);
        // gemm1: A=ZB bf16 -> TB bf16, stats S1/Q1
        mgemm_kernel<true, false, true, false, false><<<gblocks, 256, 0, stream>>>(
            nullptr, ZB, WT + (size_t)(1 + i) * H * H, b1 + (size_t)i * H,
            nullptr, nullptr, nullptr, nullptr, invN,
            TB, N, S1, Q1, nullptr, nullptr);
        // gemm2: A=TB bf16 with BN1-affine+relu -> UB bf16, stats S2/Q2
        mgemm_kernel<true, true, true, false, false><<<gblocks, 256, 0, stream>>>(
            nullptr, TB, WT + (size_t)(1 + L + i) * H * H, b2 + (size_t)i * H,
            S1, Q1, g1 + (size_t)i * H, be1 + (size_t)i * H, invN,
            UB, N, S2, Q2, nullptr, nullptr);
        statsv_kernel<<<256, 256, 0, stream>>>(UB, snorm, S2, Q2,
                                               ga + (size_t)i * H, ba + (size_t)i * H, invN, N, S3, Q3);
        tail_kernel<<<(N + 31) / 32, 256, 0, stream>>>(Hb, UB, snorm,
                                                       S2, Q2, ga + (size_t)i * H, ba + (size_t)i * H,
                                                       S3, Q3, gl + (size_t)i * H, bl + (size_t)i * H,
                                                       invN, gids, POOL + (size_t)(i + 1) * G * H, N);
    }
    final_kernel<<<G, H, 0, stream>>>(POOL, predW, predB, (float*)d_out);
}

// Round 14
// 673.388 us; speedup vs baseline: 1.3282x; 1.0294x over previous
//
#include <hip/hip_runtime.h>

#define HD __device__ __forceinline__

static constexpr int H = 128;
static constexpr int G = 100;
static constexpr int L = 4;
static constexpr int C = 10;
static constexpr int DEGCAP = 64;   // per-node edge capacity (mean deg = 12)

typedef __attribute__((ext_vector_type(8))) short short8;   // 8 bf16 (4 VGPRs)
typedef __attribute__((ext_vector_type(4))) float f32x4;    // MFMA C/D

HD float bf2f(unsigned int u16) {  // low 16 bits = bf16
    return __uint_as_float(u16 << 16);
}
HD unsigned int f2bf(float f) {    // RNE pack to 16 bits
    unsigned int u = __float_as_uint(f);
    u += 0x7fffu + ((u >> 16) & 1u);
    return u >> 16;
}

// ---------------- prep: weight transpose (blocks 0..575) + edge-table fill (blocks 576..) ----------------
__global__ __launch_bounds__(256) void prep_kernel(
    const float* __restrict__ embW, const float* __restrict__ W1, const float* __restrict__ W2,
    unsigned short* __restrict__ WT, unsigned short* __restrict__ Hb,
    const int* __restrict__ src, const int* __restrict__ dst, int E,
    int* __restrict__ cnt, int* __restrict__ esrc) {
    int b = blockIdx.x;
    if (b < 576) {
        int mat = b >> 6;
        int bx = b & 63;
        if (b == 0 && threadIdx.x < 64)
            ((unsigned int*)Hb)[threadIdx.x] = 0u;   // zero row 0 (gather null target)
        const float* s = (mat == 0) ? embW
                       : (mat <= L) ? W1 + (size_t)(mat - 1) * H * H
                                    : W2 + (size_t)(mat - 1 - L) * H * H;
        int t = bx * 256 + threadIdx.x;   // 0..16383
        int col = t >> 7, k = t & 127;
        WT[(size_t)mat * H * H + col * H + k] = (unsigned short)f2bf(s[(size_t)k * H + col]);
    } else {
        int e = (b - 576) * 256 + threadIdx.x;
        if (e < E) {
            int d = dst[e];
            int pos = atomicAdd(&cnt[d], 1) & (DEGCAP - 1);
            esrc[(size_t)d * DEGCAP + pos] = src[e] + 1;   // +1: 0 = zero row
        }
    }
}

// ---------------- fused agg + gemm1: 1024 thr / 16 waves, 64 rows x 128 cols per block ----------------
// Gather: wave w handles nodes row0+w*4..+3 (4 nodes/wave, 32 waves/CU at 2 blocks/CU -> max MLP).
// MFMA: wave w = rows (w>>2)*16..+15, cols (w&3)*32..+31 (8 MFMAs).
// Stats: shfl reduce -> LDS combine (As reused) -> one atomic per column.
__global__ __launch_bounds__(1024, 2) void aggemm_kernel(
    const unsigned short* __restrict__ HbZ, const int* __restrict__ cnt,
    const int* __restrict__ esrc, const float* __restrict__ eps, int layer,
    const unsigned short* __restrict__ WT, const float* __restrict__ bias,
    unsigned short* __restrict__ outB, int N,
    float* __restrict__ sum_out, float* __restrict__ sq_out) {
    __shared__ unsigned short As[64 * 136];   // 17408 B; reused as float scratch post-MFMA
    int tid = threadIdx.x;
    int w = tid >> 6, lane = tid & 63, q = lane >> 4, m = lane & 15;
    int row0 = blockIdx.x * 64;

    // ---- gather phase: wave w fills As rows w*4..w*4+3 (padded-16 rounds, lane = 2 cols) ----
    {
        const unsigned int* H2 = (const unsigned int*)HbZ;
        float e1 = 1.0f + eps[layer];
#pragma unroll
        for (int i = 0; i < 4; ++i) {
            int r = w * 4 + i;
            int node = row0 + r;
            unsigned int out = 0;
            if (node < N) {
                unsigned int hv = H2[(size_t)(node + 1) * 64 + lane];
                float ax = e1 * bf2f(hv & 0xffffu);
                float ay = e1 * bf2f(hv >> 16);
                int deg = min(cnt[node], DEGCAP);
                int degPad = min((deg + 15) & ~15, DEGCAP);
                const int* ep = esrc + (size_t)node * DEGCAP;
                for (int j = 0; j < degPad; j += 16) {
                    unsigned int v[16];
#pragma unroll
                    for (int u = 0; u < 16; ++u) v[u] = H2[(size_t)ep[j + u] * 64 + lane];
                    float sx[4] = {0.f, 0.f, 0.f, 0.f}, sy[4] = {0.f, 0.f, 0.f, 0.f};
#pragma unroll
                    for (int u = 0; u < 16; ++u) {
                        sx[u & 3] += bf2f(v[u] & 0xffffu);
                        sy[u & 3] += bf2f(v[u] >> 16);
                    }
                    ax += (sx[0] + sx[1]) + (sx[2] + sx[3]);
                    ay += (sy[0] + sy[1]) + (sy[2] + sy[3]);
                }
                out = f2bf(ax) | (f2bf(ay) << 16);
            }
            *(unsigned int*)&As[r * 136 + lane * 2] = out;
        }
    }
    __syncthreads();

    // ---- MFMA phase: wave w = rows (w>>2)*16..+15, cols (w&3)*32..+31 ----
    int mrow = (w >> 2) * 16;
    int colbase = (w & 3) * 32;
    short8 bfrag[2][4];
#pragma unroll
    for (int nt = 0; nt < 2; ++nt) {
        const unsigned short* wc = WT + (size_t)(colbase + nt * 16 + m) * H;
#pragma unroll
        for (int kk = 0; kk < 4; ++kk)
            bfrag[nt][kk] = *(const short8*)&wc[kk * 32 + q * 8];
    }
    f32x4 acc[2] = {(f32x4){0.f, 0.f, 0.f, 0.f}, (f32x4){0.f, 0.f, 0.f, 0.f}};
#pragma unroll
    for (int kk = 0; kk < 4; ++kk) {
        short8 af = *(const short8*)&As[(mrow + m) * 136 + kk * 32 + q * 8];
#pragma unroll
        for (int nt = 0; nt < 2; ++nt)
            acc[nt] = __builtin_amdgcn_mfma_f32_16x16x32_bf16(af, bfrag[nt][kk], acc[nt], 0, 0, 0);
    }

    // ---- epilogue: bias, bf16 store, per-wave stats ----
    float bs2[2] = {bias[colbase + m], bias[colbase + 16 + m]};
    float s[2] = {0.f, 0.f}, qq[2] = {0.f, 0.f};
#pragma unroll
    for (int nt = 0; nt < 2; ++nt) {
        int gcol = colbase + nt * 16 + m;
#pragma unroll
        for (int rg = 0; rg < 4; ++rg) {
            int grow = row0 + mrow + q * 4 + rg;
            float v = acc[nt][rg] + bs2[nt];
            if (grow < N) {
                outB[(size_t)grow * H + gcol] = (unsigned short)f2bf(v);
                s[nt] += v;
                qq[nt] += v * v;
            }
        }
    }
#pragma unroll
    for (int nt = 0; nt < 2; ++nt) {
        s[nt] += __shfl_xor(s[nt], 16); s[nt] += __shfl_xor(s[nt], 32);
        qq[nt] += __shfl_xor(qq[nt], 16); qq[nt] += __shfl_xor(qq[nt], 32);
    }
    // combine 4 row-group waves per column in LDS (reuse As), then one atomic per column
    __syncthreads();   // all MFMA reads of As complete
    float* SS = (float*)As;          // [4][128]
    float* QQ = SS + 4 * H;          // [4][128]
    if (q == 0) {
#pragma unroll
        for (int nt = 0; nt < 2; ++nt) {
            int col = colbase + nt * 16 + m;
            SS[(w >> 2) * H + col] = s[nt];
            QQ[(w >> 2) * H + col] = qq[nt];
        }
    }
    __syncthreads();
    if (tid < H) {
        atomicAdd(&sum_out[tid], SS[tid] + SS[H + tid] + SS[2 * H + tid] + SS[3 * H + tid]);
        atomicAdd(&sq_out[tid], QQ[tid] + QQ[H + tid] + QQ[2 * H + tid] + QQ[3 * H + tid]);
    }
}

// ---------------- MFMA GEMM: out = f(A) @ W + bias ----------------
template <bool ABF16, bool TRANS, bool STATS, bool POOLF, bool HOFF>
__global__ __launch_bounds__(256, 4) void mgemm_kernel(
    const float* __restrict__ Af, const unsigned short* __restrict__ Ab,
    const unsigned short* __restrict__ WT, const float* __restrict__ bias,
    const float* __restrict__ sum_in, const float* __restrict__ sq_in,
    const float* __restrict__ gam, const float* __restrict__ bet, float invN,
    unsigned short* __restrict__ outB,
    int N, float* __restrict__ sum_out, float* __restrict__ sq_out,
    const int* __restrict__ gids, float* __restrict__ pool) {
    __shared__ unsigned short As[64 * 136];
    __shared__ float cas[H], ccs[H];
    int tid = threadIdx.x;
    int w = tid >> 6, lane = tid & 63, q = lane >> 4, m = lane & 15;
    int row0 = blockIdx.x * 64;
    int colbase = w * 32;

    short8 bfrag[2][4];
#pragma unroll
    for (int nt = 0; nt < 2; ++nt) {
        const unsigned short* wc = WT + (size_t)(colbase + nt * 16 + m) * H;
#pragma unroll
        for (int kk = 0; kk < 4; ++kk)
            bfrag[nt][kk] = *(const short8*)&wc[kk * 32 + q * 8];
    }

    if (TRANS) {
        if (tid < H) {
            float mu = sum_in[tid] * invN;
            float var = sq_in[tid] * invN - mu * mu;
            float inv = rsqrtf(var + 1e-5f);
            float a = gam[tid] * inv;
            cas[tid] = a;
            ccs[tid] = bet[tid] - mu * a;
        }
        __syncthreads();
    }

    {
        int cc = tid & 15, rg = tid >> 4;
        int c0 = cc * 8;
        float a8[8], b8[8];
        if (TRANS) {
#pragma unroll
            for (int j = 0; j < 8; ++j) { a8[j] = cas[c0 + j]; b8[j] = ccs[c0 + j]; }
        }
#pragma unroll
        for (int rr = 0; rr < 4; ++rr) {
            int r = rg * 4 + rr;
            int gr = row0 + r;
            uint4 o = {0u, 0u, 0u, 0u};
            if (ABF16 && !TRANS) {
                if (gr < N) o = *(const uint4*)&Ab[(size_t)gr * H + c0];
            } else {
                float v[8] = {0.f, 0.f, 0.f, 0.f, 0.f, 0.f, 0.f, 0.f};
                if (gr < N) {
                    if (ABF16) {
                        uint4 x = *(const uint4*)&Ab[(size_t)gr * H + c0];
                        v[0] = bf2f(x.x & 0xffffu); v[1] = bf2f(x.x >> 16);
                        v[2] = bf2f(x.y & 0xffffu); v[3] = bf2f(x.y >> 16);
                        v[4] = bf2f(x.z & 0xffffu); v[5] = bf2f(x.z >> 16);
                        v[6] = bf2f(x.w & 0xffffu); v[7] = bf2f(x.w >> 16);
                    } else {
                        float4 x0 = *(const float4*)&Af[(size_t)gr * H + c0];
                        float4 x1 = *(const float4*)&Af[(size_t)gr * H + c0 + 4];
                        v[0] = x0.x; v[1] = x0.y; v[2] = x0.z; v[3] = x0.w;
                        v[4] = x1.x; v[5] = x1.y; v[6] = x1.z; v[7] = x1.w;
                    }
                }
                if (TRANS) {
#pragma unroll
                    for (int j = 0; j < 8; ++j) v[j] = fmaxf(a8[j] * v[j] + b8[j], 0.f);
                }
                o.x = f2bf(v[0]) | (f2bf(v[1]) << 16);
                o.y = f2bf(v[2]) | (f2bf(v[3]) << 16);
                o.z = f2bf(v[4]) | (f2bf(v[5]) << 16);
                o.w = f2bf(v[6]) | (f2bf(v[7]) << 16);
            }
            *(uint4*)&As[r * 136 + c0] = o;
        }
    }
    __syncthreads();

    f32x4 acc[4][2];
#pragma unroll
    for (int mt = 0; mt < 4; ++mt)
#pragma unroll
        for (int nt = 0; nt < 2; ++nt) acc[mt][nt] = (f32x4){0.f, 0.f, 0.f, 0.f};
#pragma unroll
    for (int kk = 0; kk < 4; ++kk) {
        short8 af[4];
#pragma unroll
        for (int mt = 0; mt < 4; ++mt)
            af[mt] = *(const short8*)&As[(mt * 16 + m) * 136 + kk * 32 + q * 8];
#pragma unroll
        for (int mt = 0; mt < 4; ++mt)
#pragma unroll
            for (int nt = 0; nt < 2; ++nt)
                acc[mt][nt] = __builtin_amdgcn_mfma_f32_16x16x32_bf16(
                    af[mt], bfrag[nt][kk], acc[mt][nt], 0, 0, 0);
    }

    float bs2[2] = {bias[colbase + m], bias[colbase + 16 + m]};
    float s[2] = {0.f, 0.f}, qq[2] = {0.f, 0.f};
#pragma unroll
    for (int mt = 0; mt < 4; ++mt)
#pragma unroll
        for (int nt = 0; nt < 2; ++nt) {
            int gcol = colbase + nt * 16 + m;
#pragma unroll
            for (int rg = 0; rg < 4; ++rg) {
                int grow = row0 + mt * 16 + q * 4 + rg;
                float v = acc[mt][nt][rg] + bs2[nt];
                if (grow < N) {
                    outB[(size_t)(HOFF ? grow + 1 : grow) * H + gcol] = (unsigned short)f2bf(v);
                    if (STATS || POOLF) {
                        s[nt] += v;
                        if (STATS) qq[nt] += v * v;
                    }
                }
            }
        }

    if (STATS) {
#pragma unroll
        for (int nt = 0; nt < 2; ++nt) {
            float sv = s[nt], qv = qq[nt];
            sv += __shfl_xor(sv, 16); sv += __shfl_xor(sv, 32);
            qv += __shfl_xor(qv, 16); qv += __shfl_xor(qv, 32);
            if (q == 0) {
                atomicAdd(&sum_out[colbase + nt * 16 + m], sv);
                atomicAdd(&sq_out[colbase + nt * 16 + m], qv);
            }
        }
    }

    if (POOLF) {
        int last = min(row0 + 63, N - 1);
        bool uni = (gids[row0] == gids[last]);
        if (uni) {
            int g = gids[row0];
#pragma unroll
            for (int nt = 0; nt < 2; ++nt) {
                float sv = s[nt];
                sv += __shfl_xor(sv, 16); sv += __shfl_xor(sv, 32);
                if (q == 0) atomicAdd(&pool[g * H + colbase + nt * 16 + m], sv);
            }
        } else {
#pragma unroll
            for (int mt = 0; mt < 4; ++mt)
#pragma unroll
                for (int nt = 0; nt < 2; ++nt)
#pragma unroll
                    for (int rg = 0; rg < 4; ++rg) {
                        int grow = row0 + mt * 16 + q * 4 + rg;
                        if (grow < N) {
                            float v = acc[mt][nt][rg] + bs2[nt];
                            atomicAdd(&pool[gids[grow] * H + colbase + nt * 16 + m], v);
                        }
                    }
        }
    }
}

// ---------------- stats of v = relu(ca*U+cc)*snorm, coeffs computed inline ----------------
__global__ __launch_bounds__(256) void statsv_kernel(const unsigned short* __restrict__ UB,
                                                     const float* __restrict__ snorm,
                                                     const float* __restrict__ sum2, const float* __restrict__ sq2,
                                                     const float* __restrict__ ga, const float* __restrict__ ba,
                                                     float invN, int N,
                                                     float* __restrict__ sum3, float* __restrict__ sq3) {
    __shared__ float cas[H], ccs[H];
    int t = threadIdx.x;
    if (t < H) {
        float m = sum2[t] * invN;
        float var = sq2[t] * invN - m * m;
        float inv = rsqrtf(var + 1e-5f);
        float a = ga[t] * inv;
        cas[t] = a;
        ccs[t] = ba[t] - m * a;
    }
    __syncthreads();
    int col2 = t & 63, part = t >> 6;
    int c0 = col2 * 2, c1 = c0 + 1;
    float a0 = cas[c0], b0 = ccs[c0], a1 = cas[c1], b1 = ccs[c1];
    float s0 = 0.f, q0 = 0.f, s1 = 0.f, q1 = 0.f;
    const unsigned int* U2 = (const unsigned int*)UB;
    for (int r = blockIdx.x * 4 + part; r < N; r += gridDim.x * 4) {
        float sn = snorm[r];
        unsigned int v = U2[(size_t)r * 64 + col2];
        float v0 = fmaxf(a0 * bf2f(v & 0xffffu) + b0, 0.f) * sn;
        float v1 = fmaxf(a1 * bf2f(v >> 16) + b1, 0.f) * sn;
        s0 += v0; q0 += v0 * v0;
        s1 += v1; q1 += v1 * v1;
    }
    __shared__ float S[4][H], Q[4][H];
    S[part][c0] = s0; S[part][c1] = s1;
    Q[part][c0] = q0; Q[part][c1] = q1;
    __syncthreads();
    if (t < H) {
        atomicAdd(&sum3[t], S[0][t] + S[1][t] + S[2][t] + S[3][t]);
        atomicAdd(&sq3[t], Q[0][t] + Q[1][t] + Q[2][t] + Q[3][t]);
    }
}

// ---------------- residual tail (bf16 residual, rows shifted +1) + fused pooling ----------------
__global__ __launch_bounds__(256) void tail_kernel(unsigned short* __restrict__ HbZ,
                                                   const unsigned short* __restrict__ UB,
                                                   const float* __restrict__ snorm,
                                                   const float* __restrict__ sum2, const float* __restrict__ sq2,
                                                   const float* __restrict__ ga, const float* __restrict__ ba,
                                                   const float* __restrict__ sum3, const float* __restrict__ sq3,
                                                   const float* __restrict__ gl, const float* __restrict__ bl,
                                                   float invN, const int* __restrict__ gids,
                                                   float* __restrict__ pool, int N) {
    __shared__ float ca2[H], cc2[H], ca3[H], cc3[H];
    __shared__ float PS[8][H];
    int t = threadIdx.x;
    if (t < H) {
        float m2 = sum2[t] * invN, v2 = sq2[t] * invN - m2 * m2;
        float i2 = rsqrtf(v2 + 1e-5f), a2 = ga[t] * i2;
        ca2[t] = a2; cc2[t] = ba[t] - m2 * a2;
        float m3 = sum3[t] * invN, v3 = sq3[t] * invN - m3 * m3;
        float i3 = rsqrtf(v3 + 1e-5f), a3 = gl[t] * i3;
        ca3[t] = a3; cc3[t] = bl[t] - m3 * a3;
    }
    __syncthreads();
    int row0 = blockIdx.x * 32;
    int col4 = t & 31, rowg = t >> 5;
    int c0 = col4 * 4;
    float A2[4], B2[4], A3[4], B3[4];
#pragma unroll
    for (int j = 0; j < 4; ++j) {
        A2[j] = ca2[c0 + j]; B2[j] = cc2[c0 + j];
        A3[j] = ca3[c0 + j]; B3[j] = cc3[c0 + j];
    }
    bool uni = (gids[row0] == gids[min(row0 + 31, N - 1)]);
    float p[4] = {0.f, 0.f, 0.f, 0.f};
    const uint2* U4 = (const uint2*)UB;
    uint2* H4 = (uint2*)HbZ;
#pragma unroll
    for (int rr = 0; rr < 4; ++rr) {
        int r = row0 + rowg * 4 + rr;
        if (r < N) {
            float sn = snorm[r];
            uint2 uv = U4[(size_t)r * 32 + col4];
            uint2 hv = H4[(size_t)(r + 1) * 32 + col4];
            float u[4] = {bf2f(uv.x & 0xffffu), bf2f(uv.x >> 16), bf2f(uv.y & 0xffffu), bf2f(uv.y >> 16)};
            float h[4] = {bf2f(hv.x & 0xffffu), bf2f(hv.x >> 16), bf2f(hv.y & 0xffffu), bf2f(hv.y >> 16)};
#pragma unroll
            for (int j = 0; j < 4; ++j) {
                float v = fmaxf(A2[j] * u[j] + B2[j], 0.f) * sn;
                h[j] += fmaxf(A3[j] * v + B3[j], 0.f);
            }
            uint2 hb;
            hb.x = f2bf(h[0]) | (f2bf(h[1]) << 16);
            hb.y = f2bf(h[2]) | (f2bf(h[3]) << 16);
            H4[(size_t)(r + 1) * 32 + col4] = hb;
            if (uni) {
                p[0] += h[0]; p[1] += h[1]; p[2] += h[2]; p[3] += h[3];
            } else {
                int g = gids[r];
#pragma unroll
                for (int j = 0; j < 4; ++j) atomicAdd(&pool[g * H + c0 + j], h[j]);
            }
        }
    }
    if (uni) {
#pragma unroll
        for (int j = 0; j < 4; ++j) PS[rowg][c0 + j] = p[j];
        __syncthreads();
        if (t < H) {
            float s = PS[0][t] + PS[1][t] + PS[2][t] + PS[3][t] +
                      PS[4][t] + PS[5][t] + PS[6][t] + PS[7][t];
            atomicAdd(&pool[gids[row0] * H + t], s);
        }
    }
}

// ---------------- final: score = sum_i pooled_i @ predW_i + predb_i ----------------
__global__ void final_kernel(const float* __restrict__ pool, const float* __restrict__ pw,
                             const float* __restrict__ pb, float* __restrict__ out) {
    int g = blockIdx.x, t = threadIdx.x;
    __shared__ float p[H];
    float acc = 0.f;
    for (int i = 0; i <= L; ++i) {
        p[t] = pool[(size_t)(i * G + g) * H + t];
        __syncthreads();
        if (t < C) {
            float s = 0.f;
            for (int f = 0; f < H; ++f) s += p[f] * pw[(size_t)(i * H + f) * C + t];
            acc += s + pb[i * C + t];
        }
        __syncthreads();
    }
    if (t < C) out[g * C + t] = acc;
}

extern "C" void kernel_launch(void* const* d_in, const int* in_sizes, int n_in,
                              void* d_out, int out_size, void* d_ws, size_t ws_size,
                              hipStream_t stream) {
    const float* h_in  = (const float*)d_in[0];
    const float* snorm = (const float*)d_in[1];
    const int* esrc_in = (const int*)d_in[2];
    const int* edst_in = (const int*)d_in[3];
    const int* gids    = (const int*)d_in[4];
    const float* embW = (const float*)d_in[5];
    const float* embB = (const float*)d_in[6];
    const float* eps  = (const float*)d_in[7];
    const float* W1   = (const float*)d_in[8];
    const float* b1   = (const float*)d_in[9];
    const float* g1   = (const float*)d_in[10];
    const float* be1  = (const float*)d_in[11];
    const float* W2   = (const float*)d_in[12];
    const float* b2   = (const float*)d_in[13];
    const float* ga   = (const float*)d_in[14];
    const float* ba   = (const float*)d_in[15];
    const float* gl   = (const float*)d_in[16];
    const float* bl   = (const float*)d_in[17];
    const float* predW = (const float*)d_in[18];
    const float* predB = (const float*)d_in[19];

    const int N = in_sizes[0] / H;  // 50000
    const int E = in_sizes[2];      // 600000
    const float invN = 1.0f / (float)N;

    // ws layout: [zeroed: POOL | STATS | CNT | ESRC] [WT] [Hb (N+1 rows)] [ZB] [TB]
    float* ws = (float*)d_ws;
    float* POOL = ws;                                        // (L+1)*G*H
    float* STATS = POOL + (size_t)(L + 1) * G * H;           // L*6*H
    int* CNT = (int*)(STATS + (size_t)L * 6 * H);            // N
    int* ESRC = CNT + N;                                     // N*DEGCAP (pre-zeroed => pad -> row 0)
    unsigned short* WT = (unsigned short*)(ESRC + (size_t)N * DEGCAP);  // 9*H*H bf16
    unsigned short* Hb = WT + (size_t)9 * H * H;             // (N+1)*H bf16, row 0 = zeros
    unsigned short* ZB = Hb + (size_t)(N + 1) * H;           // N*H bf16 (UB)
    unsigned short* TB = ZB + (size_t)N * H;                 // N*H bf16
    unsigned short* UB = ZB;

    size_t zbytes = ((size_t)(L + 1) * G * H + (size_t)L * 6 * H + N + (size_t)N * DEGCAP) * 4;
    hipMemsetAsync(POOL, 0, zbytes, stream);

    int prep_blocks = 576 + (E + 255) / 256;
    prep_kernel<<<prep_blocks, 256, 0, stream>>>(embW, W1, W2, WT, Hb,
                                                 esrc_in, edst_in, E, CNT, ESRC);

    int gblocks = (N + 63) / 64;
    // embedding: A=f32 h_in -> Hb rows 1..N, fused pool into POOL[0]
    mgemm_kernel<false, false, false, true, true><<<gblocks, 256, 0, stream>>>(
        h_in, nullptr, WT, embB, nullptr, nullptr, nullptr, nullptr, invN,
        Hb, N, nullptr, nullptr, gids, POOL);

    for (int i = 0; i < L; ++i) {
        float* S1 = STATS + (size_t)i * 6 * H;
        float* Q1 = S1 + H;
        float* S2 = Q1 + H;
        float* Q2 = S2 + H;
        float* S3 = Q2 + H;
        float* Q3 = S3 + H;
        // fused agg + gemm1 (16 waves, 4 nodes/wave, max occupancy): gather -> MFMA -> TB, stats S1/Q1
        aggemm_kernel<<<gblocks, 1024, 0, stream>>>(
            Hb, CNT, ESRC, eps, i, WT + (size_t)(1 + i) * H * H, b1 + (size_t)i * H,
            TB, N, S1, Q1);
        // gemm2: A=TB bf16 with BN1-affine+relu -> UB bf16, stats S2/Q2
        mgemm_kernel<true, true, true, false, false><<<gblocks, 256, 0, stream>>>(
            nullptr, TB, WT + (size_t)(1 + L + i) * H * H, b2 + (size_t)i * H,
            S1, Q1, g1 + (size_t)i * H, be1 + (size_t)i * H, invN,
            UB, N, S2, Q2, nullptr, nullptr);
        statsv_kernel<<<256, 256, 0, stream>>>(UB, snorm, S2, Q2,
                                               ga + (size_t)i * H, ba + (size_t)i * H, invN, N, S3, Q3);
        tail_kernel<<<(N + 31) / 32, 256, 0, stream>>>(Hb, UB, snorm,
                                                       S2, Q2, ga + (size_t)i * H, ba + (size_t)i * H,
                                                       S3, Q3, gl + (size_t)i * H, bl + (size_t)i * H,
                                                       invN, gids, POOL + (size_t)(i + 1) * G * H, N);
    }
    final_kernel<<<G, H, 0, stream>>>(POOL, predW, predB, (float*)d_out);
}